// Round 8
// baseline (142.925 us; speedup 1.0000x reference)
//
#include <hip/hip_runtime.h>
#include <math.h>

#define BB 2
#define LL 2048
#define DD 256
#define PP 32
#define NC 64
#define PI_F 3.14159265358979323846f

typedef __attribute__((ext_vector_type(8))) short bf16x8;
typedef __attribute__((ext_vector_type(4))) float f32x4;
typedef unsigned short ushort_t;
typedef unsigned int uint_t;

__device__ inline ushort_t f2bf(float x) {
    uint_t u = __float_as_uint(x);
    uint_t r = (u + 0x7fffu + ((u >> 16) & 1u)) >> 16;
    return (ushort_t)r;
}

// 16B-chunk XOR swizzle (Guideline 4): col is a multiple of 8 ushorts.
__device__ inline int swzc(int row, int col) {
    return (col & ~63) | ((((col >> 3) & 7) ^ (row & 7)) << 3);
}
// element-granular variant (for scalar writes)
__device__ inline int swze(int row, int col) {
    return (col & ~63) | (col & 7) | ((((col >> 3) & 7) ^ (row & 7)) << 3);
}

// ---------------------------------------------------------------------------
// Kernel A: prep (weight transposes to bf16 [N][K]) + encode_key (MFMA).
// ---------------------------------------------------------------------------
__global__ __launch_bounds__(256) void prep_key_kernel(
    const float* __restrict__ W1, const float* __restrict__ W2,
    const float* __restrict__ Wo, const float* __restrict__ valW,
    const float* __restrict__ x, const float* __restrict__ key_W,
    const float* __restrict__ key_b,
    ushort_t* __restrict__ W1t, ushort_t* __restrict__ W2t,
    ushort_t* __restrict__ Wot, ushort_t* __restrict__ valWt,
    float2* __restrict__ ph)
{
    const int bid = blockIdx.x;
    const int t = threadIdx.x;
    if (bid < 96) {
        __shared__ float T[64][65];
        const float* W; ushort_t* Wt; int K, N, tile;
        if (bid < 32)      { W = W1;   Wt = W1t;   K = 256; N = 512; tile = bid; }
        else if (bid < 64) { W = W2;   Wt = W2t;   K = 512; N = 256; tile = bid - 32; }
        else if (bid < 80) { W = Wo;   Wt = Wot;   K = 256; N = 256; tile = bid - 64; }
        else               { W = valW; Wt = valWt; K = 256; N = 256; tile = bid - 80; }
        const int ntiles = N / 64;
        const int k0 = (tile / ntiles) * 64, n0 = (tile % ntiles) * 64;
        {
            const int rr = t >> 2, cb = (t & 3) * 16;
            #pragma unroll
            for (int i = 0; i < 16; i += 4) {
                const float4 v = *(const float4*)&W[(k0 + rr) * N + n0 + cb + i];
                T[rr][cb + i + 0] = v.x; T[rr][cb + i + 1] = v.y;
                T[rr][cb + i + 2] = v.z; T[rr][cb + i + 3] = v.w;
            }
        }
        __syncthreads();
        {
            const int n = t >> 2, kb = (t & 3) * 16;
            #pragma unroll
            for (int i = 0; i < 16; ++i)
                Wt[(n0 + n) * K + k0 + kb + i] = f2bf(T[kb + i][n]);
        }
    } else {
        __shared__ ushort_t xt[16][264];
        __shared__ ushort_t kwT[32][264];
        __shared__ float rbuf[4][2][16][17];
        const int row0 = (bid - 96) * 16;
        {
            const int l = t >> 4, cb = (t & 15) * 16;
            const float* src = &x[(long)(row0 + l) * DD + cb];
            ushort_t tmp[16];
            #pragma unroll
            for (int i = 0; i < 4; ++i) {
                const float4 v = *(const float4*)&src[i * 4];
                tmp[i*4+0] = f2bf(v.x); tmp[i*4+1] = f2bf(v.y);
                tmp[i*4+2] = f2bf(v.z); tmp[i*4+3] = f2bf(v.w);
            }
            *(uint4*)&xt[l][cb]     = *(uint4*)&tmp[0];
            *(uint4*)&xt[l][cb + 8] = *(uint4*)&tmp[8];
        }
        {
            #pragma unroll
            for (int i = 0; i < 8; ++i) {
                const int idx4 = i * 256 + t;
                const int k = idx4 >> 3, pc = (idx4 & 7) * 4;
                const float4 v = *(const float4*)&key_W[k * 32 + pc];
                kwT[pc + 0][k] = f2bf(v.x);
                kwT[pc + 1][k] = f2bf(v.y);
                kwT[pc + 2][k] = f2bf(v.z);
                kwT[pc + 3][k] = f2bf(v.w);
            }
        }
        __syncthreads();
        const int wv = t >> 6, lane = t & 63;
        const int qd = lane >> 4, mc = lane & 15;
        f32x4 acc0 = {0.f,0.f,0.f,0.f}, acc1 = {0.f,0.f,0.f,0.f};
        #pragma unroll
        for (int ks = 0; ks < 2; ++ks) {
            const int ko = wv * 64 + ks * 32 + qd * 8;
            const bf16x8 a  = *(const bf16x8*)&xt[mc][ko];
            const bf16x8 b0 = *(const bf16x8*)&kwT[mc][ko];
            const bf16x8 b1 = *(const bf16x8*)&kwT[16 + mc][ko];
            acc0 = __builtin_amdgcn_mfma_f32_16x16x32_bf16(a, b0, acc0, 0, 0, 0);
            acc1 = __builtin_amdgcn_mfma_f32_16x16x32_bf16(a, b1, acc1, 0, 0, 0);
        }
        #pragma unroll
        for (int r = 0; r < 4; ++r) {
            rbuf[wv][0][qd * 4 + r][mc] = acc0[r];
            rbuf[wv][1][qd * 4 + r][mc] = acc1[r];
        }
        __syncthreads();
        #pragma unroll
        for (int rep = 0; rep < 2; ++rep) {
            const int idx = rep * 256 + t;
            const int p = idx & 31, l = idx >> 5;
            const int nf = p >> 4, mcol = p & 15;
            float a = key_b[p] + rbuf[0][nf][l][mcol] + rbuf[1][nf][l][mcol]
                    + rbuf[2][nf][l][mcol] + rbuf[3][nf][l][mcol];
            a = tanhf(a) * PI_F;
            float sn, cs;
            sincosf(a, &sn, &cs);
            ph[(long)(row0 + l) * PP + p] = make_float2(cs, sn);
        }
    }
}

// ---------------------------------------------------------------------------
// Kernel B: valbind. Block = (b, chunk c, d-quarter dq); grid 512.
// ---------------------------------------------------------------------------
__global__ __launch_bounds__(256) void valbind_kernel(
    const float* __restrict__ x, const float2* __restrict__ ph,
    const ushort_t* __restrict__ valWt, const float* __restrict__ val_b,
    ushort_t* __restrict__ VoddT, float* __restrict__ Mt)
{
    __shared__ ushort_t xsb[16][264];
    __shared__ ushort_t VdT[64][40];
    __shared__ ushort_t phsT[64][40];
    __shared__ float    Ms[64][68];

    const int tid = threadIdx.x;
    const int bid = blockIdx.x;
    const int b  = bid >> 8;
    const int c  = (bid >> 2) & 63;
    const int dq = bid & 3;
    const int base = b * LL;
    const int r0 = 32 * c;

    {
        const int j = tid >> 4, cb = (tid & 15) * 16;
        const float* src = &x[(long)(base + r0 + 2 * j + 1) * DD + cb];
        ushort_t tmp[16];
        #pragma unroll
        for (int i = 0; i < 4; ++i) {
            const float4 v = *(const float4*)&src[i * 4];
            tmp[i*4+0] = f2bf(v.x); tmp[i*4+1] = f2bf(v.y);
            tmp[i*4+2] = f2bf(v.z); tmp[i*4+3] = f2bf(v.w);
        }
        *(uint4*)&xsb[j][cb]     = *(uint4*)&tmp[0];
        *(uint4*)&xsb[j][cb + 8] = *(uint4*)&tmp[8];
    }
    {
        const int j = tid >> 4, qb = (tid & 15) * 4;
        const float4 v = *(const float4*)((const float*)ph +
                              (long)(base + r0 + 2 * j) * 64 + qb);
        phsT[qb + 0][j] = f2bf(v.x);
        phsT[qb + 1][j] = f2bf(v.y);
        phsT[qb + 2][j] = f2bf(v.z);
        phsT[qb + 3][j] = f2bf(v.w);
    }
    for (int e = tid; e < 64 * 16; e += 256) {
        phsT[e >> 4][16 + (e & 15)] = 0;
        VdT[e >> 4][16 + (e & 15)] = 0;
    }
    __syncthreads();

    const int wv = tid >> 6, lane = tid & 63;
    const int qd = lane >> 4, mc = lane & 15;

    f32x4 va = {0.f,0.f,0.f,0.f};
    const int dloc = wv * 16 + mc;
    const int ng = dq * 64 + dloc;
    const ushort_t* B0 = &valWt[(long)ng * 256];
    #pragma unroll
    for (int ks = 0; ks < 8; ++ks) {
        const bf16x8 a  = *(const bf16x8*)&xsb[mc][ks * 32 + qd * 8];
        const bf16x8 b0 = *(const bf16x8*)&B0[ks * 32 + qd * 8];
        va = __builtin_amdgcn_mfma_f32_16x16x32_bf16(a, b0, va, 0, 0, 0);
    }
    {
        const float bb = val_b[ng];
        #pragma unroll
        for (int r = 0; r < 4; ++r)
            VdT[dloc][qd * 4 + r] = f2bf(va[r] + bb);
    }
    __syncthreads();

    const bf16x8 a2 = *(const bf16x8*)&phsT[wv * 16 + mc][qd * 8];
    f32x4 macc[4];
    #pragma unroll
    for (int nf = 0; nf < 4; ++nf) {
        f32x4 z = {0.f,0.f,0.f,0.f};
        const bf16x8 b2 = *(const bf16x8*)&VdT[nf * 16 + mc][qd * 8];
        macc[nf] = __builtin_amdgcn_mfma_f32_16x16x32_bf16(a2, b2, z, 0, 0, 0);
    }
    #pragma unroll
    for (int nf = 0; nf < 4; ++nf) {
        #pragma unroll
        for (int r = 0; r < 4; ++r)
            Ms[nf * 16 + mc][wv * 16 + qd * 4 + r] = macc[nf][r];
    }
    __syncthreads();

    {
        float* dst = &Mt[((long)(b * NC + c) * 256 + dq * 64) * 64];
        #pragma unroll
        for (int p = 0; p < 4; ++p) {
            const int idx4 = p * 256 + tid;
            const int dl = idx4 >> 4, q4 = (idx4 & 15) * 4;
            *(float4*)&dst[dl * 64 + q4] = *(const float4*)&Ms[dl][q4];
        }
    }
    if (tid < 64) {
        ushort_t* vd = &VoddT[((long)(b * NC + c) * 256 + dq * 64 + tid) * 16];
        *(uint4*)&vd[0] = *(const uint4*)&VdT[tid][0];
        *(uint4*)&vd[8] = *(const uint4*)&VdT[tid][8];
    }
}

// ---------------------------------------------------------------------------
// Kernel C: prefix. EXCLUSIVE scan of Mt over chunk c -> bf16 Mpre_b.
// ---------------------------------------------------------------------------
__global__ __launch_bounds__(256) void prefix_kernel(
    const float* __restrict__ M, ushort_t* __restrict__ Mpre_b)
{
    __shared__ float segsum[4][64];
    const int tid = threadIdx.x;
    const int b  = blockIdx.x >> 8;
    const int cg = blockIdx.x & 255;
    const int col = cg * 64 + (tid & 63);
    const int seg = tid >> 6;
    const long base = (long)b * NC * 16384 + col;

    float v[16], s = 0.f;
    #pragma unroll
    for (int i = 0; i < 16; ++i) {
        v[i] = M[base + (long)(seg * 16 + i) * 16384];
        s += v[i];
    }
    segsum[seg][tid & 63] = s;
    __syncthreads();
    float run = 0.f;
    #pragma unroll
    for (int sg = 0; sg < 3; ++sg)
        if (sg < seg) run += segsum[sg][tid & 63];
    #pragma unroll
    for (int i = 0; i < 16; ++i) {
        const long a = base + (long)(seg * 16 + i) * 16384;
        Mpre_b[a] = f2bf(run);
        run += v[i];
    }
}

// ---------------------------------------------------------------------------
// Kernel D: fused retrieve + LN1 + MLP, 512 threads (8 waves, 2 waves/SIMD).
// B-tiles (Mpre, W1t, W2t, Wot) are WAVE-PRIVATE (wave wv reads only rows
// wv*32..wv*32+31), so they stage into a per-wave LDS region with NO block
// barriers: in-wave lgkmcnt orders ds_write->ds_read, and next-tile global
// loads issue right after the ds_write -- nothing drains them (no barrier in
// the loop), giving true load/MFMA overlap. Barriers: 45 -> 7 (LN handoffs).
// ---------------------------------------------------------------------------
__global__ __launch_bounds__(512) void retrieve_mlp_kernel(
    const float* __restrict__ ph, const ushort_t* __restrict__ Mpre_b,
    const ushort_t* __restrict__ VoddT,
    const float* __restrict__ ln1_g, const float* __restrict__ ln1_b,
    const ushort_t* __restrict__ W1t, const float* __restrict__ b1,
    const ushort_t* __restrict__ W2t, const float* __restrict__ b2,
    const float* __restrict__ ln2_g, const float* __restrict__ ln2_b,
    const ushort_t* __restrict__ Wot, const float* __restrict__ bo,
    const float* __restrict__ x, float* __restrict__ out)
{
    __shared__ ushort_t Wbuf[8][32][64]; // per-wave B stage, swizzled (32KB)
    __shared__ ushort_t Bs_v[256][32];   // swizzled (4-chunk XOR)
    __shared__ ushort_t As_ph[16][64];   // swizzled
    __shared__ ushort_t Bs_sh[16][64];   // swizzled
    __shared__ ushort_t As_p[16][40];    // 80B stride
    __shared__ float    refct[16][264];
    __shared__ ushort_t rhat_s[16][256]; // swizzled
    __shared__ ushort_t h_s[16][512];    // swizzled
    __shared__ ushort_t shT[16][256];    // swizzled

    const int tid = threadIdx.x;
    const int b = blockIdx.x >> 7;
    const int c = (blockIdx.x >> 1) & 63;
    const int h = blockIdx.x & 1;
    const int l0g = 32 * c + 16 * h;
    const long rowbase = (long)b * LL + l0g;

    const int wv = tid >> 6, lane = tid & 63;   // wv in [0,8)
    const int qd = lane >> 4, mc = lane & 15;
    const int m7 = mc & 7;
    const int ch = lane & 7, rl8 = lane >> 3;        // staging lane coords
    const int wcol = 8 * (ch ^ rl8);                 // swizzled stage col

    // ---- issue wave-private Mpre loads FIRST (overlap all other staging) --
    const ushort_t* msrc = &Mpre_b[(long)(b * NC + c) * 16384];
    uint4 pre[4];
    #pragma unroll
    for (int p = 0; p < 4; ++p)
        pre[p] = *(const uint4*)&msrc[(wv * 32 + p * 8 + rl8) * 64 + ch * 8];

    if (tid < 256) {   // stage As_ph + Bs_sh (swizzled uint2 writes)
        const int r = tid >> 4, q4 = (tid & 15) * 4;
        const int c4 = swze(r, q4);
        const float4 vv = *(const float4*)((const float*)ph + (rowbase + r) * 64 + q4);
        ushort_t t0[4] = {f2bf(vv.x), f2bf(vv.y), f2bf(vv.z), f2bf(vv.w)};
        *(uint2*)&As_ph[r][c4] = *(uint2*)t0;
        const float4 w = *(const float4*)((const float*)ph +
                             ((long)b * LL + 32 * c + 2 * r) * 64 + q4);
        ushort_t t1[4] = {f2bf(w.x), f2bf(w.y), f2bf(w.z), f2bf(w.w)};
        *(uint2*)&Bs_sh[r][c4] = *(uint2*)t1;
    }
    {   // stage Bs_v (4-chunk XOR) + zero pads
        const ushort_t* src = &VoddT[(long)(b * NC + c) * 4096];
        const int rw = tid >> 1, cch = tid & 1;
        *(uint4*)&Bs_v[rw][8 * (cch ^ (rw & 3))] = *(const uint4*)&src[tid * 8];
        *(uint4*)&Bs_v[rw][8 * ((2 + cch) ^ (rw & 3))] = make_uint4(0, 0, 0, 0);
        if (tid < 256) As_p[tid >> 4][16 + (tid & 15)] = 0;
    }
    // ---- wave-private Mpre -> Wbuf (no barrier needed; in-wave ordering) --
    #pragma unroll
    for (int p = 0; p < 4; ++p)
        *(uint4*)&Wbuf[wv][p * 8 + rl8][wcol] = pre[p];
    __syncthreads();                                            // B1

    // ---- S scores (wave 0 keeps result) ----
    {
        f32x4 sacc = {0.f, 0.f, 0.f, 0.f};
        #pragma unroll
        for (int ks = 0; ks < 2; ++ks) {
            const int lc = 8 * ((ks * 4 + qd) ^ m7);
            const bf16x8 a  = *(const bf16x8*)&As_ph[mc][lc];
            const bf16x8 bb = *(const bf16x8*)&Bs_sh[mc][lc];
            sacc = __builtin_amdgcn_mfma_f32_16x16x32_bf16(a, bb, sacc, 0, 0, 0);
        }
        if (wv == 0) {
            #pragma unroll
            for (int r = 0; r < 4; ++r) {
                const int l = qd * 4 + r;
                As_p[l][mc] = (2 * mc + 1 <= 16 * h + l) ? f2bf(sacc[r])
                                                         : (ushort_t)0;
            }
        }
    }

    // ---- main contraction: B from wave-private Wbuf ----
    f32x4 acc[2];
    #pragma unroll
    for (int i = 0; i < 2; ++i) acc[i] = (f32x4){0.f, 0.f, 0.f, 0.f};
    #pragma unroll
    for (int i = 0; i < 2; ++i) {
        #pragma unroll
        for (int ks = 0; ks < 2; ++ks) {
            const int lc = 8 * ((ks * 4 + qd) ^ m7);
            const bf16x8 a  = *(const bf16x8*)&As_ph[mc][lc];
            const bf16x8 bb = *(const bf16x8*)&Wbuf[wv][i * 16 + mc][lc];
            acc[i] = __builtin_amdgcn_mfma_f32_16x16x32_bf16(a, bb, acc[i], 0, 0, 0);
        }
    }
    __syncthreads();                                            // B2 (As_p ready)

    // ---- within-chunk correction ----
    {
        const bf16x8 a2 = *(const bf16x8*)&As_p[mc][qd * 8];
        #pragma unroll
        for (int i = 0; i < 2; ++i) {
            const int d0 = wv * 32 + i * 16;
            const bf16x8 b2 = *(const bf16x8*)&Bs_v[d0 + mc][8 * (qd ^ (mc & 3))];
            acc[i] = __builtin_amdgcn_mfma_f32_16x16x32_bf16(a2, b2, acc[i], 0, 0, 0);
        }
    }

    // ---- scale -> refct ----
    #pragma unroll
    for (int r = 0; r < 4; ++r) {
        const int l = qd * 4 + r;
        int va = (l0g + l + 1) >> 1; if (va < 1) va = 1;
        const float sc = 0.17677669529663687f * rsqrtf((float)va);
        #pragma unroll
        for (int i = 0; i < 2; ++i)
            refct[l][wv * 32 + i * 16 + mc] = acc[i][r] * sc;
    }
    __syncthreads();                                            // B3

    // ---- prologue: first W1 tile loads (hide under LN1) ----
    #pragma unroll
    for (int p = 0; p < 4; ++p)
        pre[p] = *(const uint4*)&W1t[(long)(wv * 32 + p * 8 + rl8) * 256 + ch * 8];

    // ---- LN1 -> rhat_s (swizzled write) ----
    {
        const int row = tid >> 5, cg = (tid & 31) * 8;
        float s = 0.f, sq = 0.f;
        #pragma unroll
        for (int i = 0; i < 8; ++i) {
            const float v = refct[row][cg + i];
            s += v; sq += v * v;
        }
        s += __shfl_xor(s, 1, 32);  sq += __shfl_xor(sq, 1, 32);
        s += __shfl_xor(s, 2, 32);  sq += __shfl_xor(sq, 2, 32);
        s += __shfl_xor(s, 4, 32);  sq += __shfl_xor(sq, 4, 32);
        s += __shfl_xor(s, 8, 32);  sq += __shfl_xor(sq, 8, 32);
        s += __shfl_xor(s, 16, 32); sq += __shfl_xor(sq, 16, 32);
        const float m = s * (1.f / 256.f);
        const float inv = rsqrtf(sq * (1.f / 256.f) - m * m + 1e-5f);
        ushort_t o16[8];
        #pragma unroll
        for (int i = 0; i < 8; ++i) {
            const int cc = cg + i;
            o16[i] = f2bf((refct[row][cc] - m) * inv * ln1_g[cc] + ln1_b[cc]);
        }
        *(uint4*)&rhat_s[row][swzc(row, cg)] = *(uint4*)&o16[0];
    }
    __syncthreads();                                            // B4

    // ---- gemm1: h = gelu(rhat @ W1^T + b1); wave-private pipelined ----
    {
        f32x4 acc1[2];
        acc1[0] = (f32x4){0.f,0.f,0.f,0.f};
        acc1[1] = (f32x4){0.f,0.f,0.f,0.f};
        #pragma unroll
        for (int t = 0; t < 8; ++t) {
            const int k0 = (t & 3) * 64;
            #pragma unroll
            for (int p = 0; p < 4; ++p)
                *(uint4*)&Wbuf[wv][p * 8 + rl8][wcol] = pre[p];
            if (t < 7) {
                const int nhn = (t + 1) >> 2, k0n = ((t + 1) & 3) * 64;
                #pragma unroll
                for (int p = 0; p < 4; ++p)
                    pre[p] = *(const uint4*)&W1t[(long)(nhn * 256 + wv * 32 + p * 8 + rl8) * 256 + k0n + ch * 8];
            } else {   // prefetch first W2 tile
                #pragma unroll
                for (int p = 0; p < 4; ++p)
                    pre[p] = *(const uint4*)&W2t[(long)(wv * 32 + p * 8 + rl8) * 512 + ch * 8];
            }
            #pragma unroll
            for (int ks = 0; ks < 2; ++ks) {
                const int lc = 8 * ((ks * 4 + qd) ^ m7);
                const bf16x8 a = *(const bf16x8*)&rhat_s[mc][k0 + lc];
                #pragma unroll
                for (int nf = 0; nf < 2; ++nf) {
                    const bf16x8 bb = *(const bf16x8*)&Wbuf[wv][nf * 16 + mc][lc];
                    acc1[nf] = __builtin_amdgcn_mfma_f32_16x16x32_bf16(a, bb, acc1[nf], 0, 0, 0);
                }
            }
            if ((t & 3) == 3) {
                const int nh = t >> 2;
                #pragma unroll
                for (int nf = 0; nf < 2; ++nf) {
                    const int n = nh * 256 + wv * 32 + nf * 16 + mc;
                    const float bb = b1[n];
                    #pragma unroll
                    for (int r = 0; r < 4; ++r) {
                        float v = acc1[nf][r] + bb;
                        v = 0.5f * v * (1.f + erff(v * 0.70710678118654752f));
                        const int rw = qd * 4 + r;
                        h_s[rw][swze(rw, n)] = f2bf(v);
                    }
                    acc1[nf] = (f32x4){0.f,0.f,0.f,0.f};
                }
            }
        }
    }
    __syncthreads();                                            // B5

    // ---- gemm2: refined = h @ W2^T + b2; wave-private pipelined ----
    f32x4 acc2[2];
    acc2[0] = (f32x4){0.f,0.f,0.f,0.f};
    acc2[1] = (f32x4){0.f,0.f,0.f,0.f};
    #pragma unroll
    for (int it = 0; it < 8; ++it) {
        const int k0 = it * 64;
        #pragma unroll
        for (int p = 0; p < 4; ++p)
            *(uint4*)&Wbuf[wv][p * 8 + rl8][wcol] = pre[p];
        if (it < 7) {
            #pragma unroll
            for (int p = 0; p < 4; ++p)
                pre[p] = *(const uint4*)&W2t[(long)(wv * 32 + p * 8 + rl8) * 512 + k0 + 64 + ch * 8];
        } else {   // prefetch first Wo tile
            #pragma unroll
            for (int p = 0; p < 4; ++p)
                pre[p] = *(const uint4*)&Wot[(long)(wv * 32 + p * 8 + rl8) * 256 + ch * 8];
        }
        #pragma unroll
        for (int ks = 0; ks < 2; ++ks) {
            const int lc = 8 * ((ks * 4 + qd) ^ m7);
            const bf16x8 a = *(const bf16x8*)&h_s[mc][k0 + lc];
            #pragma unroll
            for (int nf = 0; nf < 2; ++nf) {
                const bf16x8 bb = *(const bf16x8*)&Wbuf[wv][nf * 16 + mc][lc];
                acc2[nf] = __builtin_amdgcn_mfma_f32_16x16x32_bf16(a, bb, acc2[nf], 0, 0, 0);
            }
        }
    }
    #pragma unroll
    for (int nf = 0; nf < 2; ++nf) {
        const int n = wv * 32 + nf * 16 + mc;
        const float bb = b2[n];
        #pragma unroll
        for (int r = 0; r < 4; ++r)
            refct[qd * 4 + r][n] = acc2[nf][r] + bb;
    }
    __syncthreads();                                            // B6

    // ---- LN2 -> shT (swizzled write) ----
    {
        const int row = tid >> 5, cg = (tid & 31) * 8;
        float s = 0.f, sq = 0.f;
        #pragma unroll
        for (int i = 0; i < 8; ++i) {
            const float v = refct[row][cg + i];
            s += v; sq += v * v;
        }
        s += __shfl_xor(s, 1, 32);  sq += __shfl_xor(sq, 1, 32);
        s += __shfl_xor(s, 2, 32);  sq += __shfl_xor(sq, 2, 32);
        s += __shfl_xor(s, 4, 32);  sq += __shfl_xor(sq, 4, 32);
        s += __shfl_xor(s, 8, 32);  sq += __shfl_xor(sq, 8, 32);
        s += __shfl_xor(s, 16, 32); sq += __shfl_xor(sq, 16, 32);
        const float m = s * (1.f / 256.f);
        const float inv = rsqrtf(sq * (1.f / 256.f) - m * m + 1e-5f);
        ushort_t o16[8];
        #pragma unroll
        for (int i = 0; i < 8; ++i) {
            const int cc = cg + i;
            o16[i] = f2bf((refct[row][cc] - m) * inv * ln2_g[cc] + ln2_b[cc]);
        }
        *(uint4*)&shT[row][swzc(row, cg)] = *(uint4*)&o16[0];
    }
    __syncthreads();                                            // B7

    // ---- gemm3: out = x + shT @ Wo^T + bo; wave-private pipelined ----
    f32x4 acc3[2];
    acc3[0] = (f32x4){0.f,0.f,0.f,0.f};
    acc3[1] = (f32x4){0.f,0.f,0.f,0.f};
    #pragma unroll
    for (int it = 0; it < 4; ++it) {
        const int k0 = it * 64;
        #pragma unroll
        for (int p = 0; p < 4; ++p)
            *(uint4*)&Wbuf[wv][p * 8 + rl8][wcol] = pre[p];
        if (it < 3) {
            #pragma unroll
            for (int p = 0; p < 4; ++p)
                pre[p] = *(const uint4*)&Wot[(long)(wv * 32 + p * 8 + rl8) * 256 + k0 + 64 + ch * 8];
        }
        #pragma unroll
        for (int ks = 0; ks < 2; ++ks) {
            const int lc = 8 * ((ks * 4 + qd) ^ m7);
            const bf16x8 a = *(const bf16x8*)&shT[mc][k0 + lc];
            #pragma unroll
            for (int nf = 0; nf < 2; ++nf) {
                const bf16x8 bb = *(const bf16x8*)&Wbuf[wv][nf * 16 + mc][lc];
                acc3[nf] = __builtin_amdgcn_mfma_f32_16x16x32_bf16(a, bb, acc3[nf], 0, 0, 0);
            }
        }
    }
    #pragma unroll
    for (int nf = 0; nf < 2; ++nf) {
        const int n = wv * 32 + nf * 16 + mc;
        const float bb = bo[n];
        #pragma unroll
        for (int r = 0; r < 4; ++r) {
            const long row = rowbase + qd * 4 + r;
            out[row * DD + n] = acc3[nf][r] + bb + x[row * DD + n];
        }
    }
}

// ---------------------------------------------------------------------------
extern "C" void kernel_launch(void* const* d_in, const int* in_sizes, int n_in,
                              void* d_out, int out_size, void* d_ws, size_t ws_size,
                              hipStream_t stream)
{
    const float* x     = (const float*)d_in[0];
    const float* key_W = (const float*)d_in[1];
    const float* key_b = (const float*)d_in[2];
    const float* val_W = (const float*)d_in[3];
    const float* val_b = (const float*)d_in[4];
    const float* ln1_g = (const float*)d_in[5];
    const float* ln1_b = (const float*)d_in[6];
    const float* W1    = (const float*)d_in[7];
    const float* b1    = (const float*)d_in[8];
    const float* W2    = (const float*)d_in[9];
    const float* b2    = (const float*)d_in[10];
    const float* ln2_g = (const float*)d_in[11];
    const float* ln2_b = (const float*)d_in[12];
    const float* Wo    = (const float*)d_in[13];
    const float* bo    = (const float*)d_in[14];
    float* outp = (float*)d_out;

    float* ws = (float*)d_ws;
    float*  ph      = ws;                             // 262144 f32 (1 MB)
    float*  Mt      = ws + 262144;                    // 2097152 f32 (8 MB)
    ushort_t* Mpre_b = (ushort_t*)(Mt + 2097152);     // 2097152 us (4 MB)
    ushort_t* VoddT  = Mpre_b + 2097152;              // 524288 us (1 MB)
    ushort_t* rhat_b = VoddT + 524288;                // (layout hold)
    ushort_t* W1t   = rhat_b + 1048576;               // 131072 us
    ushort_t* W2t   = W1t + 131072;
    ushort_t* Wot   = W2t + 131072;
    ushort_t* valWt = Wot + 65536;

    prep_key_kernel<<<352, 256, 0, stream>>>(W1, W2, Wo, val_W, x, key_W, key_b,
                                             W1t, W2t, Wot, valWt, (float2*)ph);
    valbind_kernel<<<512, 256, 0, stream>>>(x, (const float2*)ph, valWt, val_b,
                                            VoddT, Mt);
    prefix_kernel<<<512, 256, 0, stream>>>(Mt, Mpre_b);
    retrieve_mlp_kernel<<<256, 512, 0, stream>>>(ph, Mpre_b, VoddT, ln1_g, ln1_b,
                                                 W1t, b1, W2t, b2, ln2_g, ln2_b,
                                                 Wot, bo, x, outp);
}

// Round 9
// 122.968 us; speedup vs baseline: 1.1623x; 1.1623x over previous
//
#include <hip/hip_runtime.h>
#include <math.h>

#define BB 2
#define LL 2048
#define DD 256
#define PP 32
#define NC 64
#define PI_F 3.14159265358979323846f

typedef __attribute__((ext_vector_type(8))) short bf16x8;
typedef __attribute__((ext_vector_type(4))) float f32x4;
typedef unsigned short ushort_t;
typedef unsigned int uint_t;

__device__ inline ushort_t f2bf(float x) {
    uint_t u = __float_as_uint(x);
    uint_t r = (u + 0x7fffu + ((u >> 16) & 1u)) >> 16;
    return (ushort_t)r;
}

// 16B-chunk XOR swizzle (Guideline 4): col is a multiple of 8 ushorts.
__device__ inline int swzc(int row, int col) {
    return (col & ~63) | ((((col >> 3) & 7) ^ (row & 7)) << 3);
}
// element-granular variant (for scalar/sub-chunk writes)
__device__ inline int swze(int row, int col) {
    return (col & ~63) | (col & 7) | ((((col >> 3) & 7) ^ (row & 7)) << 3);
}

// ---------------------------------------------------------------------------
// Kernel A: prep (weight transposes to bf16 [N][K]) + encode_key (MFMA).
// ---------------------------------------------------------------------------
__global__ __launch_bounds__(256) void prep_key_kernel(
    const float* __restrict__ W1, const float* __restrict__ W2,
    const float* __restrict__ Wo, const float* __restrict__ valW,
    const float* __restrict__ x, const float* __restrict__ key_W,
    const float* __restrict__ key_b,
    ushort_t* __restrict__ W1t, ushort_t* __restrict__ W2t,
    ushort_t* __restrict__ Wot, ushort_t* __restrict__ valWt,
    float2* __restrict__ ph)
{
    const int bid = blockIdx.x;
    const int t = threadIdx.x;
    if (bid < 96) {
        __shared__ float T[64][65];
        const float* W; ushort_t* Wt; int K, N, tile;
        if (bid < 32)      { W = W1;   Wt = W1t;   K = 256; N = 512; tile = bid; }
        else if (bid < 64) { W = W2;   Wt = W2t;   K = 512; N = 256; tile = bid - 32; }
        else if (bid < 80) { W = Wo;   Wt = Wot;   K = 256; N = 256; tile = bid - 64; }
        else               { W = valW; Wt = valWt; K = 256; N = 256; tile = bid - 80; }
        const int ntiles = N / 64;
        const int k0 = (tile / ntiles) * 64, n0 = (tile % ntiles) * 64;
        {
            const int rr = t >> 2, cb = (t & 3) * 16;
            #pragma unroll
            for (int i = 0; i < 16; i += 4) {
                const float4 v = *(const float4*)&W[(k0 + rr) * N + n0 + cb + i];
                T[rr][cb + i + 0] = v.x; T[rr][cb + i + 1] = v.y;
                T[rr][cb + i + 2] = v.z; T[rr][cb + i + 3] = v.w;
            }
        }
        __syncthreads();
        {
            const int n = t >> 2, kb = (t & 3) * 16;
            #pragma unroll
            for (int i = 0; i < 16; ++i)
                Wt[(n0 + n) * K + k0 + kb + i] = f2bf(T[kb + i][n]);
        }
    } else {
        __shared__ ushort_t xt[16][264];
        __shared__ ushort_t kwT[32][264];
        __shared__ float rbuf[4][2][16][17];
        const int row0 = (bid - 96) * 16;
        {
            const int l = t >> 4, cb = (t & 15) * 16;
            const float* src = &x[(long)(row0 + l) * DD + cb];
            ushort_t tmp[16];
            #pragma unroll
            for (int i = 0; i < 4; ++i) {
                const float4 v = *(const float4*)&src[i * 4];
                tmp[i*4+0] = f2bf(v.x); tmp[i*4+1] = f2bf(v.y);
                tmp[i*4+2] = f2bf(v.z); tmp[i*4+3] = f2bf(v.w);
            }
            *(uint4*)&xt[l][cb]     = *(uint4*)&tmp[0];
            *(uint4*)&xt[l][cb + 8] = *(uint4*)&tmp[8];
        }
        {
            #pragma unroll
            for (int i = 0; i < 8; ++i) {
                const int idx4 = i * 256 + t;
                const int k = idx4 >> 3, pc = (idx4 & 7) * 4;
                const float4 v = *(const float4*)&key_W[k * 32 + pc];
                kwT[pc + 0][k] = f2bf(v.x);
                kwT[pc + 1][k] = f2bf(v.y);
                kwT[pc + 2][k] = f2bf(v.z);
                kwT[pc + 3][k] = f2bf(v.w);
            }
        }
        __syncthreads();
        const int wv = t >> 6, lane = t & 63;
        const int qd = lane >> 4, mc = lane & 15;
        f32x4 acc0 = {0.f,0.f,0.f,0.f}, acc1 = {0.f,0.f,0.f,0.f};
        #pragma unroll
        for (int ks = 0; ks < 2; ++ks) {
            const int ko = wv * 64 + ks * 32 + qd * 8;
            const bf16x8 a  = *(const bf16x8*)&xt[mc][ko];
            const bf16x8 b0 = *(const bf16x8*)&kwT[mc][ko];
            const bf16x8 b1 = *(const bf16x8*)&kwT[16 + mc][ko];
            acc0 = __builtin_amdgcn_mfma_f32_16x16x32_bf16(a, b0, acc0, 0, 0, 0);
            acc1 = __builtin_amdgcn_mfma_f32_16x16x32_bf16(a, b1, acc1, 0, 0, 0);
        }
        #pragma unroll
        for (int r = 0; r < 4; ++r) {
            rbuf[wv][0][qd * 4 + r][mc] = acc0[r];
            rbuf[wv][1][qd * 4 + r][mc] = acc1[r];
        }
        __syncthreads();
        #pragma unroll
        for (int rep = 0; rep < 2; ++rep) {
            const int idx = rep * 256 + t;
            const int p = idx & 31, l = idx >> 5;
            const int nf = p >> 4, mcol = p & 15;
            float a = key_b[p] + rbuf[0][nf][l][mcol] + rbuf[1][nf][l][mcol]
                    + rbuf[2][nf][l][mcol] + rbuf[3][nf][l][mcol];
            a = tanhf(a) * PI_F;
            float sn, cs;
            sincosf(a, &sn, &cs);
            ph[(long)(row0 + l) * PP + p] = make_float2(cs, sn);
        }
    }
}

// ---------------------------------------------------------------------------
// Kernel B: valbind. Block = (b, chunk c, d-quarter dq); grid 512.
// ---------------------------------------------------------------------------
__global__ __launch_bounds__(256) void valbind_kernel(
    const float* __restrict__ x, const float2* __restrict__ ph,
    const ushort_t* __restrict__ valWt, const float* __restrict__ val_b,
    ushort_t* __restrict__ VoddT, float* __restrict__ Mt)
{
    __shared__ ushort_t xsb[16][264];
    __shared__ ushort_t VdT[64][40];
    __shared__ ushort_t phsT[64][40];
    __shared__ float    Ms[64][68];

    const int tid = threadIdx.x;
    const int bid = blockIdx.x;
    const int b  = bid >> 8;
    const int c  = (bid >> 2) & 63;
    const int dq = bid & 3;
    const int base = b * LL;
    const int r0 = 32 * c;

    {
        const int j = tid >> 4, cb = (tid & 15) * 16;
        const float* src = &x[(long)(base + r0 + 2 * j + 1) * DD + cb];
        ushort_t tmp[16];
        #pragma unroll
        for (int i = 0; i < 4; ++i) {
            const float4 v = *(const float4*)&src[i * 4];
            tmp[i*4+0] = f2bf(v.x); tmp[i*4+1] = f2bf(v.y);
            tmp[i*4+2] = f2bf(v.z); tmp[i*4+3] = f2bf(v.w);
        }
        *(uint4*)&xsb[j][cb]     = *(uint4*)&tmp[0];
        *(uint4*)&xsb[j][cb + 8] = *(uint4*)&tmp[8];
    }
    {
        const int j = tid >> 4, qb = (tid & 15) * 4;
        const float4 v = *(const float4*)((const float*)ph +
                              (long)(base + r0 + 2 * j) * 64 + qb);
        phsT[qb + 0][j] = f2bf(v.x);
        phsT[qb + 1][j] = f2bf(v.y);
        phsT[qb + 2][j] = f2bf(v.z);
        phsT[qb + 3][j] = f2bf(v.w);
    }
    for (int e = tid; e < 64 * 16; e += 256) {
        phsT[e >> 4][16 + (e & 15)] = 0;
        VdT[e >> 4][16 + (e & 15)] = 0;
    }
    __syncthreads();

    const int wv = tid >> 6, lane = tid & 63;
    const int qd = lane >> 4, mc = lane & 15;

    f32x4 va = {0.f,0.f,0.f,0.f};
    const int dloc = wv * 16 + mc;
    const int ng = dq * 64 + dloc;
    const ushort_t* B0 = &valWt[(long)ng * 256];
    #pragma unroll
    for (int ks = 0; ks < 8; ++ks) {
        const bf16x8 a  = *(const bf16x8*)&xsb[mc][ks * 32 + qd * 8];
        const bf16x8 b0 = *(const bf16x8*)&B0[ks * 32 + qd * 8];
        va = __builtin_amdgcn_mfma_f32_16x16x32_bf16(a, b0, va, 0, 0, 0);
    }
    {
        const float bb = val_b[ng];
        #pragma unroll
        for (int r = 0; r < 4; ++r)
            VdT[dloc][qd * 4 + r] = f2bf(va[r] + bb);
    }
    __syncthreads();

    const bf16x8 a2 = *(const bf16x8*)&phsT[wv * 16 + mc][qd * 8];
    f32x4 macc[4];
    #pragma unroll
    for (int nf = 0; nf < 4; ++nf) {
        f32x4 z = {0.f,0.f,0.f,0.f};
        const bf16x8 b2 = *(const bf16x8*)&VdT[nf * 16 + mc][qd * 8];
        macc[nf] = __builtin_amdgcn_mfma_f32_16x16x32_bf16(a2, b2, z, 0, 0, 0);
    }
    #pragma unroll
    for (int nf = 0; nf < 4; ++nf) {
        #pragma unroll
        for (int r = 0; r < 4; ++r)
            Ms[nf * 16 + mc][wv * 16 + qd * 4 + r] = macc[nf][r];
    }
    __syncthreads();

    {
        float* dst = &Mt[((long)(b * NC + c) * 256 + dq * 64) * 64];
        #pragma unroll
        for (int p = 0; p < 4; ++p) {
            const int idx4 = p * 256 + tid;
            const int dl = idx4 >> 4, q4 = (idx4 & 15) * 4;
            *(float4*)&dst[dl * 64 + q4] = *(const float4*)&Ms[dl][q4];
        }
    }
    if (tid < 64) {
        ushort_t* vd = &VoddT[((long)(b * NC + c) * 256 + dq * 64 + tid) * 16];
        *(uint4*)&vd[0] = *(const uint4*)&VdT[tid][0];
        *(uint4*)&vd[8] = *(const uint4*)&VdT[tid][8];
    }
}

// ---------------------------------------------------------------------------
// Kernel C: prefix. EXCLUSIVE scan of Mt over chunk c -> bf16 Mpre_b.
// ---------------------------------------------------------------------------
__global__ __launch_bounds__(256) void prefix_kernel(
    const float* __restrict__ M, ushort_t* __restrict__ Mpre_b)
{
    __shared__ float segsum[4][64];
    const int tid = threadIdx.x;
    const int b  = blockIdx.x >> 8;
    const int cg = blockIdx.x & 255;
    const int col = cg * 64 + (tid & 63);
    const int seg = tid >> 6;
    const long base = (long)b * NC * 16384 + col;

    float v[16], s = 0.f;
    #pragma unroll
    for (int i = 0; i < 16; ++i) {
        v[i] = M[base + (long)(seg * 16 + i) * 16384];
        s += v[i];
    }
    segsum[seg][tid & 63] = s;
    __syncthreads();
    float run = 0.f;
    #pragma unroll
    for (int sg = 0; sg < 3; ++sg)
        if (sg < seg) run += segsum[sg][tid & 63];
    #pragma unroll
    for (int i = 0; i < 16; ++i) {
        const long a = base + (long)(seg * 16 + i) * 16384;
        Mpre_b[a] = f2bf(run);
        run += v[i];
    }
}

// ---------------------------------------------------------------------------
// Kernel D: fused retrieve + LN1 + MLP. 1024 threads = 16 waves = 4 waves/SIMD
// (2x TLP vs round 6), keeping round-6's proven block-convoyed staging (the
// barrier convoy groups all waves' loads -> latencies overlap; r7/r8 showed
// removing it hurts). Per-wave N/d span halves to 16 cols. LNs: 64 thr/row.
// ---------------------------------------------------------------------------
__global__ __launch_bounds__(1024) void retrieve_mlp_kernel(
    const float* __restrict__ ph, const ushort_t* __restrict__ Mpre_b,
    const ushort_t* __restrict__ VoddT,
    const float* __restrict__ ln1_g, const float* __restrict__ ln1_b,
    const ushort_t* __restrict__ W1t, const float* __restrict__ b1,
    const ushort_t* __restrict__ W2t, const float* __restrict__ b2,
    const float* __restrict__ ln2_g, const float* __restrict__ ln2_b,
    const ushort_t* __restrict__ Wot, const float* __restrict__ bo,
    const float* __restrict__ x, float* __restrict__ out)
{
    __shared__ ushort_t Bs_m[256][64];   // swizzled; Mpre^T / weight B-stage
    __shared__ ushort_t Bs_v[256][32];   // swizzled (4-chunk XOR)
    __shared__ ushort_t As_ph[16][64];   // swizzled
    __shared__ ushort_t Bs_sh[16][64];   // swizzled
    __shared__ ushort_t As_p[16][40];    // 80B stride
    __shared__ float    refct[16][264];
    __shared__ ushort_t rhat_s[16][256]; // swizzled
    __shared__ ushort_t h_s[16][512];    // swizzled
    __shared__ ushort_t shT[16][256];    // swizzled

    const int tid = threadIdx.x;
    const int b = blockIdx.x >> 7;
    const int c = (blockIdx.x >> 1) & 63;
    const int h = blockIdx.x & 1;
    const int l0g = 32 * c + 16 * h;
    const long rowbase = (long)b * LL + l0g;

    {   // stage Bs_m (2048 uint4, 2/thread, swizzled write)
        const ushort_t* src = &Mpre_b[(long)(b * NC + c) * 16384];
        #pragma unroll
        for (int p = 0; p < 2; ++p) {
            const int idx8 = p * 1024 + tid;
            const int d = idx8 >> 3, ch = idx8 & 7;
            *(uint4*)&Bs_m[d][8 * (ch ^ (d & 7))] = *(const uint4*)&src[idx8 * 8];
        }
    }
    if (tid < 256) {   // stage As_ph + Bs_sh (swizzled uint2 writes)
        const int r = tid >> 4, q4 = (tid & 15) * 4;
        const int c4 = swze(r, q4);
        const float4 vv = *(const float4*)((const float*)ph + (rowbase + r) * 64 + q4);
        ushort_t t0[4] = {f2bf(vv.x), f2bf(vv.y), f2bf(vv.z), f2bf(vv.w)};
        *(uint2*)&As_ph[r][c4] = *(uint2*)t0;
        const float4 w = *(const float4*)((const float*)ph +
                             ((long)b * LL + 32 * c + 2 * r) * 64 + q4);
        ushort_t t1[4] = {f2bf(w.x), f2bf(w.y), f2bf(w.z), f2bf(w.w)};
        *(uint2*)&Bs_sh[r][c4] = *(uint2*)t1;
    }
    if (tid < 512) {   // stage Bs_v (4-chunk XOR) + zero pads
        const ushort_t* src = &VoddT[(long)(b * NC + c) * 4096];
        const int rw = tid >> 1, cch = tid & 1;
        *(uint4*)&Bs_v[rw][8 * (cch ^ (rw & 3))] = *(const uint4*)&src[tid * 8];
        *(uint4*)&Bs_v[rw][8 * ((2 + cch) ^ (rw & 3))] = make_uint4(0, 0, 0, 0);
    }
    if (tid >= 512 && tid < 768) {
        const int e = tid - 512;
        As_p[e >> 4][16 + (e & 15)] = 0;
    }
    __syncthreads();                                            // B1

    const int wv = tid >> 6, lane = tid & 63;   // wv in [0,16)
    const int qd = lane >> 4, mc = lane & 15;
    const int m7 = mc & 7;
    const int d0 = wv * 16;

    // ---- S scores (all waves compute; wave 0 keeps result) ----
    {
        f32x4 sacc = {0.f, 0.f, 0.f, 0.f};
        #pragma unroll
        for (int ks = 0; ks < 2; ++ks) {
            const int lc = 8 * ((ks * 4 + qd) ^ m7);
            const bf16x8 a  = *(const bf16x8*)&As_ph[mc][lc];
            const bf16x8 bb = *(const bf16x8*)&Bs_sh[mc][lc];
            sacc = __builtin_amdgcn_mfma_f32_16x16x32_bf16(a, bb, sacc, 0, 0, 0);
        }
        if (wv == 0) {
            #pragma unroll
            for (int r = 0; r < 4; ++r) {
                const int l = qd * 4 + r;
                As_p[l][mc] = (2 * mc + 1 <= 16 * h + l) ? f2bf(sacc[r])
                                                         : (ushort_t)0;
            }
        }
    }

    // ---- main contraction: 16 waves x 1 d-block of 16 ----
    f32x4 acc = {0.f, 0.f, 0.f, 0.f};
    #pragma unroll
    for (int ks = 0; ks < 2; ++ks) {
        const int lc = 8 * ((ks * 4 + qd) ^ m7);
        const bf16x8 a  = *(const bf16x8*)&As_ph[mc][lc];
        const bf16x8 bb = *(const bf16x8*)&Bs_m[d0 + mc][lc];
        acc = __builtin_amdgcn_mfma_f32_16x16x32_bf16(a, bb, acc, 0, 0, 0);
    }
    __syncthreads();                                            // B2 (As_p ready)

    // ---- within-chunk correction ----
    {
        const bf16x8 a2 = *(const bf16x8*)&As_p[mc][qd * 8];
        const bf16x8 b2 = *(const bf16x8*)&Bs_v[d0 + mc][8 * (qd ^ (mc & 3))];
        acc = __builtin_amdgcn_mfma_f32_16x16x32_bf16(a2, b2, acc, 0, 0, 0);
    }

    // ---- scale -> refct ----
    #pragma unroll
    for (int r = 0; r < 4; ++r) {
        const int l = qd * 4 + r;
        int va = (l0g + l + 1) >> 1; if (va < 1) va = 1;
        const float sc = 0.17677669529663687f * rsqrtf((float)va);
        refct[l][d0 + mc] = acc[r] * sc;
    }
    __syncthreads();                                            // B3

    // ---- LN1 -> rhat_s (64 threads/row, 4 cols each; full-wave reduce) ----
    {
        const int row = tid >> 6, cg = (tid & 63) * 4;
        float s = 0.f, sq = 0.f;
        #pragma unroll
        for (int i = 0; i < 4; ++i) {
            const float v = refct[row][cg + i];
            s += v; sq += v * v;
        }
        s += __shfl_xor(s, 1, 64);  sq += __shfl_xor(sq, 1, 64);
        s += __shfl_xor(s, 2, 64);  sq += __shfl_xor(sq, 2, 64);
        s += __shfl_xor(s, 4, 64);  sq += __shfl_xor(sq, 4, 64);
        s += __shfl_xor(s, 8, 64);  sq += __shfl_xor(sq, 8, 64);
        s += __shfl_xor(s, 16, 64); sq += __shfl_xor(sq, 16, 64);
        s += __shfl_xor(s, 32, 64); sq += __shfl_xor(sq, 32, 64);
        const float m = s * (1.f / 256.f);
        const float inv = rsqrtf(sq * (1.f / 256.f) - m * m + 1e-5f);
        ushort_t o4[4];
        #pragma unroll
        for (int i = 0; i < 4; ++i) {
            const int cc = cg + i;
            o4[i] = f2bf((refct[row][cc] - m) * inv * ln1_g[cc] + ln1_b[cc]);
        }
        *(uint2*)&rhat_s[row][swze(row, cg)] = *(uint2*)&o4[0];
    }
    __syncthreads();                                            // B4

    // ---- gemm1: h = gelu(rhat @ W1^T + b1); block-convoyed staging ----
    #pragma unroll
    for (int nh = 0; nh < 2; ++nh) {
        f32x4 acc1 = {0.f,0.f,0.f,0.f};
        for (int k0 = 0; k0 < 256; k0 += 64) {
            __syncthreads();
            #pragma unroll
            for (int p = 0; p < 2; ++p) {
                const int idx8 = p * 1024 + tid;
                const int d = idx8 >> 3, ch = idx8 & 7;
                *(uint4*)&Bs_m[d][8 * (ch ^ (d & 7))] =
                    *(const uint4*)&W1t[(long)(nh * 256 + d) * 256 + k0 + ch * 8];
            }
            __syncthreads();
            #pragma unroll
            for (int ks = 0; ks < 2; ++ks) {
                const int lc = 8 * ((ks * 4 + qd) ^ m7);
                const bf16x8 a  = *(const bf16x8*)&rhat_s[mc][k0 + lc];
                const bf16x8 bb = *(const bf16x8*)&Bs_m[d0 + mc][lc];
                acc1 = __builtin_amdgcn_mfma_f32_16x16x32_bf16(a, bb, acc1, 0, 0, 0);
            }
        }
        {
            const int n = nh * 256 + d0 + mc;
            const float bb = b1[n];
            #pragma unroll
            for (int r = 0; r < 4; ++r) {
                float v = acc1[r] + bb;
                v = 0.5f * v * (1.f + erff(v * 0.70710678118654752f));
                const int rw = qd * 4 + r;
                h_s[rw][swze(rw, n)] = f2bf(v);
            }
        }
    }
    __syncthreads();                                            // B5

    // ---- gemm2: refined = h @ W2^T + b2 ----
    f32x4 acc2 = {0.f,0.f,0.f,0.f};
    for (int k0 = 0; k0 < 512; k0 += 64) {
        __syncthreads();
        #pragma unroll
        for (int p = 0; p < 2; ++p) {
            const int idx8 = p * 1024 + tid;
            const int d = idx8 >> 3, ch = idx8 & 7;
            *(uint4*)&Bs_m[d][8 * (ch ^ (d & 7))] =
                *(const uint4*)&W2t[(long)d * 512 + k0 + ch * 8];
        }
        __syncthreads();
        #pragma unroll
        for (int ks = 0; ks < 2; ++ks) {
            const int lc = 8 * ((ks * 4 + qd) ^ m7);
            const bf16x8 a  = *(const bf16x8*)&h_s[mc][k0 + lc];
            const bf16x8 bb = *(const bf16x8*)&Bs_m[d0 + mc][lc];
            acc2 = __builtin_amdgcn_mfma_f32_16x16x32_bf16(a, bb, acc2, 0, 0, 0);
        }
    }
    {
        const int n = d0 + mc;
        const float bb = b2[n];
        #pragma unroll
        for (int r = 0; r < 4; ++r)
            refct[qd * 4 + r][n] = acc2[r] + bb;
    }
    __syncthreads();                                            // B6

    // ---- LN2 -> shT ----
    {
        const int row = tid >> 6, cg = (tid & 63) * 4;
        float s = 0.f, sq = 0.f;
        #pragma unroll
        for (int i = 0; i < 4; ++i) {
            const float v = refct[row][cg + i];
            s += v; sq += v * v;
        }
        s += __shfl_xor(s, 1, 64);  sq += __shfl_xor(sq, 1, 64);
        s += __shfl_xor(s, 2, 64);  sq += __shfl_xor(sq, 2, 64);
        s += __shfl_xor(s, 4, 64);  sq += __shfl_xor(sq, 4, 64);
        s += __shfl_xor(s, 8, 64);  sq += __shfl_xor(sq, 8, 64);
        s += __shfl_xor(s, 16, 64); sq += __shfl_xor(sq, 16, 64);
        s += __shfl_xor(s, 32, 64); sq += __shfl_xor(sq, 32, 64);
        const float m = s * (1.f / 256.f);
        const float inv = rsqrtf(sq * (1.f / 256.f) - m * m + 1e-5f);
        ushort_t o4[4];
        #pragma unroll
        for (int i = 0; i < 4; ++i) {
            const int cc = cg + i;
            o4[i] = f2bf((refct[row][cc] - m) * inv * ln2_g[cc] + ln2_b[cc]);
        }
        *(uint2*)&shT[row][swze(row, cg)] = *(uint2*)&o4[0];
    }
    __syncthreads();                                            // B7

    // ---- gemm3: out = x + shT @ Wo^T + bo ----
    f32x4 acc3 = {0.f,0.f,0.f,0.f};
    for (int k0 = 0; k0 < 256; k0 += 64) {
        __syncthreads();
        #pragma unroll
        for (int p = 0; p < 2; ++p) {
            const int idx8 = p * 1024 + tid;
            const int d = idx8 >> 3, ch = idx8 & 7;
            *(uint4*)&Bs_m[d][8 * (ch ^ (d & 7))] =
                *(const uint4*)&Wot[(long)d * 256 + k0 + ch * 8];
        }
        __syncthreads();
        #pragma unroll
        for (int ks = 0; ks < 2; ++ks) {
            const int lc = 8 * ((ks * 4 + qd) ^ m7);
            const bf16x8 a  = *(const bf16x8*)&shT[mc][k0 + lc];
            const bf16x8 bb = *(const bf16x8*)&Bs_m[d0 + mc][lc];
            acc3 = __builtin_amdgcn_mfma_f32_16x16x32_bf16(a, bb, acc3, 0, 0, 0);
        }
    }
    {
        const int n = d0 + mc;
        const float bb = bo[n];
        #pragma unroll
        for (int r = 0; r < 4; ++r) {
            const long row = rowbase + qd * 4 + r;
            out[row * DD + n] = acc3[r] + bb + x[row * DD + n];
        }
    }
}

// ---------------------------------------------------------------------------
extern "C" void kernel_launch(void* const* d_in, const int* in_sizes, int n_in,
                              void* d_out, int out_size, void* d_ws, size_t ws_size,
                              hipStream_t stream)
{
    const float* x     = (const float*)d_in[0];
    const float* key_W = (const float*)d_in[1];
    const float* key_b = (const float*)d_in[2];
    const float* val_W = (const float*)d_in[3];
    const float* val_b = (const float*)d_in[4];
    const float* ln1_g = (const float*)d_in[5];
    const float* ln1_b = (const float*)d_in[6];
    const float* W1    = (const float*)d_in[7];
    const float* b1    = (const float*)d_in[8];
    const float* W2    = (const float*)d_in[9];
    const float* b2    = (const float*)d_in[10];
    const float* ln2_g = (const float*)d_in[11];
    const float* ln2_b = (const float*)d_in[12];
    const float* Wo    = (const float*)d_in[13];
    const float* bo    = (const float*)d_in[14];
    float* outp = (float*)d_out;

    float* ws = (float*)d_ws;
    float*  ph      = ws;                             // 262144 f32 (1 MB)
    float*  Mt      = ws + 262144;                    // 2097152 f32 (8 MB)
    ushort_t* Mpre_b = (ushort_t*)(Mt + 2097152);     // 2097152 us (4 MB)
    ushort_t* VoddT  = Mpre_b + 2097152;              // 524288 us (1 MB)
    ushort_t* rhat_b = VoddT + 524288;                // (layout hold)
    ushort_t* W1t   = rhat_b + 1048576;               // 131072 us
    ushort_t* W2t   = W1t + 131072;
    ushort_t* Wot   = W2t + 131072;
    ushort_t* valWt = Wot + 65536;

    prep_key_kernel<<<352, 256, 0, stream>>>(W1, W2, Wo, val_W, x, key_W, key_b,
                                             W1t, W2t, Wot, valWt, (float2*)ph);
    valbind_kernel<<<512, 256, 0, stream>>>(x, (const float2*)ph, valWt, val_b,
                                            VoddT, Mt);
    prefix_kernel<<<512, 256, 0, stream>>>(Mt, Mpre_b);
    retrieve_mlp_kernel<<<256, 1024, 0, stream>>>(ph, Mpre_b, VoddT, ln1_g, ln1_b,
                                                  W1t, b1, W2t, b2, ln2_g, ln2_b,
                                                  Wot, bo, x, outp);
}

// Round 10
// 120.660 us; speedup vs baseline: 1.1845x; 1.0191x over previous
//
#include <hip/hip_runtime.h>
#include <math.h>

#define BB 2
#define LL 2048
#define DD 256
#define PP 32
#define NC 64
#define PI_F 3.14159265358979323846f

typedef __attribute__((ext_vector_type(8))) short bf16x8;
typedef __attribute__((ext_vector_type(4))) float f32x4;
typedef unsigned short ushort_t;
typedef unsigned int uint_t;

__device__ inline ushort_t f2bf(float x) {
    uint_t u = __float_as_uint(x);
    uint_t r = (u + 0x7fffu + ((u >> 16) & 1u)) >> 16;
    return (ushort_t)r;
}

// 16B-chunk XOR swizzle (Guideline 4), within each 64-ushort (128B) group.
__device__ inline int swzc(int row, int col) {
    return (col & ~63) | ((((col >> 3) & 7) ^ (row & 7)) << 3);
}
// element-granular variant (for scalar/sub-chunk writes)
__device__ inline int swze(int row, int col) {
    return (col & ~63) | (col & 7) | ((((col >> 3) & 7) ^ (row & 7)) << 3);
}

// ---------------------------------------------------------------------------
// Kernel A: prep (weight transposes to bf16 [N][K]) + encode_key (MFMA).
// ---------------------------------------------------------------------------
__global__ __launch_bounds__(256) void prep_key_kernel(
    const float* __restrict__ W1, const float* __restrict__ W2,
    const float* __restrict__ Wo, const float* __restrict__ valW,
    const float* __restrict__ x, const float* __restrict__ key_W,
    const float* __restrict__ key_b,
    ushort_t* __restrict__ W1t, ushort_t* __restrict__ W2t,
    ushort_t* __restrict__ Wot, ushort_t* __restrict__ valWt,
    float2* __restrict__ ph)
{
    const int bid = blockIdx.x;
    const int t = threadIdx.x;
    if (bid < 96) {
        __shared__ float T[64][65];
        const float* W; ushort_t* Wt; int K, N, tile;
        if (bid < 32)      { W = W1;   Wt = W1t;   K = 256; N = 512; tile = bid; }
        else if (bid < 64) { W = W2;   Wt = W2t;   K = 512; N = 256; tile = bid - 32; }
        else if (bid < 80) { W = Wo;   Wt = Wot;   K = 256; N = 256; tile = bid - 64; }
        else               { W = valW; Wt = valWt; K = 256; N = 256; tile = bid - 80; }
        const int ntiles = N / 64;
        const int k0 = (tile / ntiles) * 64, n0 = (tile % ntiles) * 64;
        {
            const int rr = t >> 2, cb = (t & 3) * 16;
            #pragma unroll
            for (int i = 0; i < 16; i += 4) {
                const float4 v = *(const float4*)&W[(k0 + rr) * N + n0 + cb + i];
                T[rr][cb + i + 0] = v.x; T[rr][cb + i + 1] = v.y;
                T[rr][cb + i + 2] = v.z; T[rr][cb + i + 3] = v.w;
            }
        }
        __syncthreads();
        {
            const int n = t >> 2, kb = (t & 3) * 16;
            #pragma unroll
            for (int i = 0; i < 16; ++i)
                Wt[(n0 + n) * K + k0 + kb + i] = f2bf(T[kb + i][n]);
        }
    } else {
        __shared__ ushort_t xt[16][264];
        __shared__ ushort_t kwT[32][264];
        __shared__ float rbuf[4][2][16][17];
        const int row0 = (bid - 96) * 16;
        {
            const int l = t >> 4, cb = (t & 15) * 16;
            const float* src = &x[(long)(row0 + l) * DD + cb];
            ushort_t tmp[16];
            #pragma unroll
            for (int i = 0; i < 4; ++i) {
                const float4 v = *(const float4*)&src[i * 4];
                tmp[i*4+0] = f2bf(v.x); tmp[i*4+1] = f2bf(v.y);
                tmp[i*4+2] = f2bf(v.z); tmp[i*4+3] = f2bf(v.w);
            }
            *(uint4*)&xt[l][cb]     = *(uint4*)&tmp[0];
            *(uint4*)&xt[l][cb + 8] = *(uint4*)&tmp[8];
        }
        {
            #pragma unroll
            for (int i = 0; i < 8; ++i) {
                const int idx4 = i * 256 + t;
                const int k = idx4 >> 3, pc = (idx4 & 7) * 4;
                const float4 v = *(const float4*)&key_W[k * 32 + pc];
                kwT[pc + 0][k] = f2bf(v.x);
                kwT[pc + 1][k] = f2bf(v.y);
                kwT[pc + 2][k] = f2bf(v.z);
                kwT[pc + 3][k] = f2bf(v.w);
            }
        }
        __syncthreads();
        const int wv = t >> 6, lane = t & 63;
        const int qd = lane >> 4, mc = lane & 15;
        f32x4 acc0 = {0.f,0.f,0.f,0.f}, acc1 = {0.f,0.f,0.f,0.f};
        #pragma unroll
        for (int ks = 0; ks < 2; ++ks) {
            const int ko = wv * 64 + ks * 32 + qd * 8;
            const bf16x8 a  = *(const bf16x8*)&xt[mc][ko];
            const bf16x8 b0 = *(const bf16x8*)&kwT[mc][ko];
            const bf16x8 b1 = *(const bf16x8*)&kwT[16 + mc][ko];
            acc0 = __builtin_amdgcn_mfma_f32_16x16x32_bf16(a, b0, acc0, 0, 0, 0);
            acc1 = __builtin_amdgcn_mfma_f32_16x16x32_bf16(a, b1, acc1, 0, 0, 0);
        }
        #pragma unroll
        for (int r = 0; r < 4; ++r) {
            rbuf[wv][0][qd * 4 + r][mc] = acc0[r];
            rbuf[wv][1][qd * 4 + r][mc] = acc1[r];
        }
        __syncthreads();
        #pragma unroll
        for (int rep = 0; rep < 2; ++rep) {
            const int idx = rep * 256 + t;
            const int p = idx & 31, l = idx >> 5;
            const int nf = p >> 4, mcol = p & 15;
            float a = key_b[p] + rbuf[0][nf][l][mcol] + rbuf[1][nf][l][mcol]
                    + rbuf[2][nf][l][mcol] + rbuf[3][nf][l][mcol];
            a = tanhf(a) * PI_F;
            float sn, cs;
            sincosf(a, &sn, &cs);
            ph[(long)(row0 + l) * PP + p] = make_float2(cs, sn);
        }
    }
}

// ---------------------------------------------------------------------------
// Kernel B: valbind. Block = (b, chunk c, d-quarter dq); grid 512.
// ---------------------------------------------------------------------------
__global__ __launch_bounds__(256) void valbind_kernel(
    const float* __restrict__ x, const float2* __restrict__ ph,
    const ushort_t* __restrict__ valWt, const float* __restrict__ val_b,
    ushort_t* __restrict__ VoddT, float* __restrict__ Mt)
{
    __shared__ ushort_t xsb[16][264];
    __shared__ ushort_t VdT[64][40];
    __shared__ ushort_t phsT[64][40];
    __shared__ float    Ms[64][68];

    const int tid = threadIdx.x;
    const int bid = blockIdx.x;
    const int b  = bid >> 8;
    const int c  = (bid >> 2) & 63;
    const int dq = bid & 3;
    const int base = b * LL;
    const int r0 = 32 * c;

    {
        const int j = tid >> 4, cb = (tid & 15) * 16;
        const float* src = &x[(long)(base + r0 + 2 * j + 1) * DD + cb];
        ushort_t tmp[16];
        #pragma unroll
        for (int i = 0; i < 4; ++i) {
            const float4 v = *(const float4*)&src[i * 4];
            tmp[i*4+0] = f2bf(v.x); tmp[i*4+1] = f2bf(v.y);
            tmp[i*4+2] = f2bf(v.z); tmp[i*4+3] = f2bf(v.w);
        }
        *(uint4*)&xsb[j][cb]     = *(uint4*)&tmp[0];
        *(uint4*)&xsb[j][cb + 8] = *(uint4*)&tmp[8];
    }
    {
        const int j = tid >> 4, qb = (tid & 15) * 4;
        const float4 v = *(const float4*)((const float*)ph +
                              (long)(base + r0 + 2 * j) * 64 + qb);
        phsT[qb + 0][j] = f2bf(v.x);
        phsT[qb + 1][j] = f2bf(v.y);
        phsT[qb + 2][j] = f2bf(v.z);
        phsT[qb + 3][j] = f2bf(v.w);
    }
    for (int e = tid; e < 64 * 16; e += 256) {
        phsT[e >> 4][16 + (e & 15)] = 0;
        VdT[e >> 4][16 + (e & 15)] = 0;
    }
    __syncthreads();

    const int wv = tid >> 6, lane = tid & 63;
    const int qd = lane >> 4, mc = lane & 15;

    f32x4 va = {0.f,0.f,0.f,0.f};
    const int dloc = wv * 16 + mc;
    const int ng = dq * 64 + dloc;
    const ushort_t* B0 = &valWt[(long)ng * 256];
    #pragma unroll
    for (int ks = 0; ks < 8; ++ks) {
        const bf16x8 a  = *(const bf16x8*)&xsb[mc][ks * 32 + qd * 8];
        const bf16x8 b0 = *(const bf16x8*)&B0[ks * 32 + qd * 8];
        va = __builtin_amdgcn_mfma_f32_16x16x32_bf16(a, b0, va, 0, 0, 0);
    }
    {
        const float bb = val_b[ng];
        #pragma unroll
        for (int r = 0; r < 4; ++r)
            VdT[dloc][qd * 4 + r] = f2bf(va[r] + bb);
    }
    __syncthreads();

    const bf16x8 a2 = *(const bf16x8*)&phsT[wv * 16 + mc][qd * 8];
    f32x4 macc[4];
    #pragma unroll
    for (int nf = 0; nf < 4; ++nf) {
        f32x4 z = {0.f,0.f,0.f,0.f};
        const bf16x8 b2 = *(const bf16x8*)&VdT[nf * 16 + mc][qd * 8];
        macc[nf] = __builtin_amdgcn_mfma_f32_16x16x32_bf16(a2, b2, z, 0, 0, 0);
    }
    #pragma unroll
    for (int nf = 0; nf < 4; ++nf) {
        #pragma unroll
        for (int r = 0; r < 4; ++r)
            Ms[nf * 16 + mc][wv * 16 + qd * 4 + r] = macc[nf][r];
    }
    __syncthreads();

    {
        float* dst = &Mt[((long)(b * NC + c) * 256 + dq * 64) * 64];
        #pragma unroll
        for (int p = 0; p < 4; ++p) {
            const int idx4 = p * 256 + tid;
            const int dl = idx4 >> 4, q4 = (idx4 & 15) * 4;
            *(float4*)&dst[dl * 64 + q4] = *(const float4*)&Ms[dl][q4];
        }
    }
    if (tid < 64) {
        ushort_t* vd = &VoddT[((long)(b * NC + c) * 256 + dq * 64 + tid) * 16];
        *(uint4*)&vd[0] = *(const uint4*)&VdT[tid][0];
        *(uint4*)&vd[8] = *(const uint4*)&VdT[tid][8];
    }
}

// ---------------------------------------------------------------------------
// Kernel C: prefix. EXCLUSIVE scan of Mt over chunk c -> bf16 Mpre_b.
// ---------------------------------------------------------------------------
__global__ __launch_bounds__(256) void prefix_kernel(
    const float* __restrict__ M, ushort_t* __restrict__ Mpre_b)
{
    __shared__ float segsum[4][64];
    const int tid = threadIdx.x;
    const int b  = blockIdx.x >> 8;
    const int cg = blockIdx.x & 255;
    const int col = cg * 64 + (tid & 63);
    const int seg = tid >> 6;
    const long base = (long)b * NC * 16384 + col;

    float v[16], s = 0.f;
    #pragma unroll
    for (int i = 0; i < 16; ++i) {
        v[i] = M[base + (long)(seg * 16 + i) * 16384];
        s += v[i];
    }
    segsum[seg][tid & 63] = s;
    __syncthreads();
    float run = 0.f;
    #pragma unroll
    for (int sg = 0; sg < 3; ++sg)
        if (sg < seg) run += segsum[sg][tid & 63];
    #pragma unroll
    for (int i = 0; i < 16; ++i) {
        const long a = base + (long)(seg * 16 + i) * 16384;
        Mpre_b[a] = f2bf(run);
        run += v[i];
    }
}

// ---------------------------------------------------------------------------
// Kernel D: fused retrieve + LN1 + MLP. Round-6 structure (512 thr, 8 waves,
// block-convoyed staging -- proven best) with K-STEP 128: Bs_m [256][128],
// staging rounds halved (gemm1 8->4, gemm2 8->4, gemm3 4->2), barriers 44->24,
// 2x outstanding loads per convoy round. Swizzle per 64-col group.
// ---------------------------------------------------------------------------
__global__ __launch_bounds__(512) void retrieve_mlp_kernel(
    const float* __restrict__ ph, const ushort_t* __restrict__ Mpre_b,
    const ushort_t* __restrict__ VoddT,
    const float* __restrict__ ln1_g, const float* __restrict__ ln1_b,
    const ushort_t* __restrict__ W1t, const float* __restrict__ b1,
    const ushort_t* __restrict__ W2t, const float* __restrict__ b2,
    const float* __restrict__ ln2_g, const float* __restrict__ ln2_b,
    const ushort_t* __restrict__ Wot, const float* __restrict__ bo,
    const float* __restrict__ x, float* __restrict__ out)
{
    __shared__ ushort_t Bs_m[256][128];  // swizzled; Mpre^T (cols 0-63) / K=128 weight stage
    __shared__ ushort_t Bs_v[256][32];   // swizzled (4-chunk XOR)
    __shared__ ushort_t As_ph[16][64];   // swizzled
    __shared__ ushort_t Bs_sh[16][64];   // swizzled
    __shared__ ushort_t As_p[16][40];    // 80B stride
    __shared__ float    refct[16][264];
    __shared__ ushort_t rhat_s[16][256]; // swizzled
    __shared__ ushort_t h_s[16][512];    // swizzled
    __shared__ ushort_t shT[16][256];    // swizzled

    const int tid = threadIdx.x;
    const int b = blockIdx.x >> 7;
    const int c = (blockIdx.x >> 1) & 63;
    const int h = blockIdx.x & 1;
    const int l0g = 32 * c + 16 * h;
    const long rowbase = (long)b * LL + l0g;

    {   // stage Bs_m cols 0..63 with Mpre (2048 uint4, 4/thread, swizzled)
        const ushort_t* src = &Mpre_b[(long)(b * NC + c) * 16384];
        #pragma unroll
        for (int p = 0; p < 4; ++p) {
            const int idx8 = p * 512 + tid;
            const int d = idx8 >> 3, ch = idx8 & 7;
            *(uint4*)&Bs_m[d][8 * (ch ^ (d & 7))] = *(const uint4*)&src[idx8 * 8];
        }
    }
    if (tid < 256) {   // stage As_ph + Bs_sh (swizzled uint2 writes)
        const int r = tid >> 4, q4 = (tid & 15) * 4;
        const int c4 = swze(r, q4);
        const float4 vv = *(const float4*)((const float*)ph + (rowbase + r) * 64 + q4);
        ushort_t t0[4] = {f2bf(vv.x), f2bf(vv.y), f2bf(vv.z), f2bf(vv.w)};
        *(uint2*)&As_ph[r][c4] = *(uint2*)t0;
        const float4 w = *(const float4*)((const float*)ph +
                             ((long)b * LL + 32 * c + 2 * r) * 64 + q4);
        ushort_t t1[4] = {f2bf(w.x), f2bf(w.y), f2bf(w.z), f2bf(w.w)};
        *(uint2*)&Bs_sh[r][c4] = *(uint2*)t1;
    }
    {   // stage Bs_v (4-chunk XOR) + zero pads
        const ushort_t* src = &VoddT[(long)(b * NC + c) * 4096];
        const int rw = tid >> 1, cch = tid & 1;
        *(uint4*)&Bs_v[rw][8 * (cch ^ (rw & 3))] = *(const uint4*)&src[tid * 8];
        *(uint4*)&Bs_v[rw][8 * ((2 + cch) ^ (rw & 3))] = make_uint4(0, 0, 0, 0);
        if (tid < 256) As_p[tid >> 4][16 + (tid & 15)] = 0;
    }
    __syncthreads();                                            // B1

    const int wv = tid >> 6, lane = tid & 63;   // wv in [0,8)
    const int qd = lane >> 4, mc = lane & 15;
    const int m7 = mc & 7;

    // ---- S scores (wave 0 keeps result) ----
    {
        f32x4 sacc = {0.f, 0.f, 0.f, 0.f};
        #pragma unroll
        for (int ks = 0; ks < 2; ++ks) {
            const int lc = 8 * ((ks * 4 + qd) ^ m7);
            const bf16x8 a  = *(const bf16x8*)&As_ph[mc][lc];
            const bf16x8 bb = *(const bf16x8*)&Bs_sh[mc][lc];
            sacc = __builtin_amdgcn_mfma_f32_16x16x32_bf16(a, bb, sacc, 0, 0, 0);
        }
        if (wv == 0) {
            #pragma unroll
            for (int r = 0; r < 4; ++r) {
                const int l = qd * 4 + r;
                As_p[l][mc] = (2 * mc + 1 <= 16 * h + l) ? f2bf(sacc[r])
                                                         : (ushort_t)0;
            }
        }
    }

    // ---- main contraction: 8 waves x 2 d-blocks of 16 ----
    f32x4 acc[2];
    #pragma unroll
    for (int i = 0; i < 2; ++i) acc[i] = (f32x4){0.f, 0.f, 0.f, 0.f};
    #pragma unroll
    for (int i = 0; i < 2; ++i) {
        const int d0 = wv * 32 + i * 16;
        #pragma unroll
        for (int ks = 0; ks < 2; ++ks) {
            const int lc = 8 * ((ks * 4 + qd) ^ m7);
            const bf16x8 a  = *(const bf16x8*)&As_ph[mc][lc];
            const bf16x8 bb = *(const bf16x8*)&Bs_m[d0 + mc][lc];
            acc[i] = __builtin_amdgcn_mfma_f32_16x16x32_bf16(a, bb, acc[i], 0, 0, 0);
        }
    }
    __syncthreads();                                            // B2 (As_p ready)

    // ---- within-chunk correction ----
    {
        const bf16x8 a2 = *(const bf16x8*)&As_p[mc][qd * 8];
        #pragma unroll
        for (int i = 0; i < 2; ++i) {
            const int d0 = wv * 32 + i * 16;
            const bf16x8 b2 = *(const bf16x8*)&Bs_v[d0 + mc][8 * (qd ^ (mc & 3))];
            acc[i] = __builtin_amdgcn_mfma_f32_16x16x32_bf16(a2, b2, acc[i], 0, 0, 0);
        }
    }

    // ---- scale -> refct ----
    #pragma unroll
    for (int r = 0; r < 4; ++r) {
        const int l = qd * 4 + r;
        int va = (l0g + l + 1) >> 1; if (va < 1) va = 1;
        const float sc = 0.17677669529663687f * rsqrtf((float)va);
        #pragma unroll
        for (int i = 0; i < 2; ++i)
            refct[l][wv * 32 + i * 16 + mc] = acc[i][r] * sc;
    }
    __syncthreads();                                            // B3

    // ---- LN1 -> rhat_s (32 threads/row, 8 cols each) ----
    {
        const int row = tid >> 5, cg = (tid & 31) * 8;
        float s = 0.f, sq = 0.f;
        #pragma unroll
        for (int i = 0; i < 8; ++i) {
            const float v = refct[row][cg + i];
            s += v; sq += v * v;
        }
        s += __shfl_xor(s, 1, 32);  sq += __shfl_xor(sq, 1, 32);
        s += __shfl_xor(s, 2, 32);  sq += __shfl_xor(sq, 2, 32);
        s += __shfl_xor(s, 4, 32);  sq += __shfl_xor(sq, 4, 32);
        s += __shfl_xor(s, 8, 32);  sq += __shfl_xor(sq, 8, 32);
        s += __shfl_xor(s, 16, 32); sq += __shfl_xor(sq, 16, 32);
        const float m = s * (1.f / 256.f);
        const float inv = rsqrtf(sq * (1.f / 256.f) - m * m + 1e-5f);
        ushort_t o16[8];
        #pragma unroll
        for (int i = 0; i < 8; ++i) {
            const int cc = cg + i;
            o16[i] = f2bf((refct[row][cc] - m) * inv * ln1_g[cc] + ln1_b[cc]);
        }
        *(uint4*)&rhat_s[row][swzc(row, cg)] = *(uint4*)&o16[0];
    }

    // ---- gemm1: h = gelu(rhat @ W1^T + b1); K-step 128, 4 rounds ----
    #pragma unroll
    for (int nh = 0; nh < 2; ++nh) {
        f32x4 acc1[2];
        acc1[0] = (f32x4){0.f,0.f,0.f,0.f};
        acc1[1] = (f32x4){0.f,0.f,0.f,0.f};
        for (int kb = 0; kb < 256; kb += 128) {
            __syncthreads();
            #pragma unroll
            for (int p = 0; p < 8; ++p) {
                const int idx = p * 512 + tid;
                const int d = idx >> 4, ch = idx & 15;
                const int pc = 8 * ((ch & 8) | ((ch & 7) ^ (d & 7)));
                *(uint4*)&Bs_m[d][pc] =
                    *(const uint4*)&W1t[(long)(nh * 256 + d) * 256 + kb + ch * 8];
            }
            __syncthreads();
            #pragma unroll
            for (int ks = 0; ks < 4; ++ks) {
                const int g = (ks >> 1) * 64;
                const int cc = g + 8 * (((ks & 1) * 4 + qd) ^ m7);
                const bf16x8 a = *(const bf16x8*)&rhat_s[mc][kb + cc];
                #pragma unroll
                for (int nf = 0; nf < 2; ++nf) {
                    const bf16x8 bb = *(const bf16x8*)&Bs_m[wv * 32 + nf * 16 + mc][cc];
                    acc1[nf] = __builtin_amdgcn_mfma_f32_16x16x32_bf16(a, bb, acc1[nf], 0, 0, 0);
                }
            }
        }
        #pragma unroll
        for (int nf = 0; nf < 2; ++nf) {
            const int n = nh * 256 + wv * 32 + nf * 16 + mc;
            const float bb = b1[n];
            #pragma unroll
            for (int r = 0; r < 4; ++r) {
                float v = acc1[nf][r] + bb;
                v = 0.5f * v * (1.f + erff(v * 0.70710678118654752f));
                const int rw = qd * 4 + r;
                h_s[rw][swze(rw, n)] = f2bf(v);
            }
        }
    }

    // ---- gemm2: refined = h @ W2^T + b2; K-step 128, 4 rounds ----
    f32x4 acc2[2];
    acc2[0] = (f32x4){0.f,0.f,0.f,0.f};
    acc2[1] = (f32x4){0.f,0.f,0.f,0.f};
    for (int kb = 0; kb < 512; kb += 128) {
        __syncthreads();
        #pragma unroll
        for (int p = 0; p < 8; ++p) {
            const int idx = p * 512 + tid;
            const int d = idx >> 4, ch = idx & 15;
            const int pc = 8 * ((ch & 8) | ((ch & 7) ^ (d & 7)));
            *(uint4*)&Bs_m[d][pc] = *(const uint4*)&W2t[(long)d * 512 + kb + ch * 8];
        }
        __syncthreads();
        #pragma unroll
        for (int ks = 0; ks < 4; ++ks) {
            const int g = (ks >> 1) * 64;
            const int cc = g + 8 * (((ks & 1) * 4 + qd) ^ m7);
            const bf16x8 a = *(const bf16x8*)&h_s[mc][kb + cc];
            #pragma unroll
            for (int nf = 0; nf < 2; ++nf) {
                const bf16x8 bb = *(const bf16x8*)&Bs_m[wv * 32 + nf * 16 + mc][cc];
                acc2[nf] = __builtin_amdgcn_mfma_f32_16x16x32_bf16(a, bb, acc2[nf], 0, 0, 0);
            }
        }
    }
    #pragma unroll
    for (int nf = 0; nf < 2; ++nf) {
        const int n = wv * 32 + nf * 16 + mc;
        const float bb = b2[n];
        #pragma unroll
        for (int r = 0; r < 4; ++r)
            refct[qd * 4 + r][n] = acc2[nf][r] + bb;
    }
    __syncthreads();                                            // B6

    // ---- LN2 -> shT (swizzled write) ----
    {
        const int row = tid >> 5, cg = (tid & 31) * 8;
        float s = 0.f, sq = 0.f;
        #pragma unroll
        for (int i = 0; i < 8; ++i) {
            const float v = refct[row][cg + i];
            s += v; sq += v * v;
        }
        s += __shfl_xor(s, 1, 32);  sq += __shfl_xor(sq, 1, 32);
        s += __shfl_xor(s, 2, 32);  sq += __shfl_xor(sq, 2, 32);
        s += __shfl_xor(s, 4, 32);  sq += __shfl_xor(sq, 4, 32);
        s += __shfl_xor(s, 8, 32);  sq += __shfl_xor(sq, 8, 32);
        s += __shfl_xor(s, 16, 32); sq += __shfl_xor(sq, 16, 32);
        const float m = s * (1.f / 256.f);
        const float inv = rsqrtf(sq * (1.f / 256.f) - m * m + 1e-5f);
        ushort_t o16[8];
        #pragma unroll
        for (int i = 0; i < 8; ++i) {
            const int cc = cg + i;
            o16[i] = f2bf((refct[row][cc] - m) * inv * ln2_g[cc] + ln2_b[cc]);
        }
        *(uint4*)&shT[row][swzc(row, cg)] = *(uint4*)&o16[0];
    }

    // ---- gemm3: out = x + shT @ Wo^T + bo; K-step 128, 2 rounds ----
    f32x4 acc3[2];
    acc3[0] = (f32x4){0.f,0.f,0.f,0.f};
    acc3[1] = (f32x4){0.f,0.f,0.f,0.f};
    for (int kb = 0; kb < 256; kb += 128) {
        __syncthreads();
        #pragma unroll
        for (int p = 0; p < 8; ++p) {
            const int idx = p * 512 + tid;
            const int d = idx >> 4, ch = idx & 15;
            const int pc = 8 * ((ch & 8) | ((ch & 7) ^ (d & 7)));
            *(uint4*)&Bs_m[d][pc] = *(const uint4*)&Wot[(long)d * 256 + kb + ch * 8];
        }
        __syncthreads();
        #pragma unroll
        for (int ks = 0; ks < 4; ++ks) {
            const int g = (ks >> 1) * 64;
            const int cc = g + 8 * (((ks & 1) * 4 + qd) ^ m7);
            const bf16x8 a = *(const bf16x8*)&shT[mc][kb + cc];
            #pragma unroll
            for (int nf = 0; nf < 2; ++nf) {
                const bf16x8 bb = *(const bf16x8*)&Bs_m[wv * 32 + nf * 16 + mc][cc];
                acc3[nf] = __builtin_amdgcn_mfma_f32_16x16x32_bf16(a, bb, acc3[nf], 0, 0, 0);
            }
        }
    }
    #pragma unroll
    for (int nf = 0; nf < 2; ++nf) {
        const int n = wv * 32 + nf * 16 + mc;
        const float bb = bo[n];
        #pragma unroll
        for (int r = 0; r < 4; ++r) {
            const long row = rowbase + qd * 4 + r;
            out[row * DD + n] = acc3[nf][r] + bb + x[row * DD + n];
        }
    }
}

// ---------------------------------------------------------------------------
extern "C" void kernel_launch(void* const* d_in, const int* in_sizes, int n_in,
                              void* d_out, int out_size, void* d_ws, size_t ws_size,
                              hipStream_t stream)
{
    const float* x     = (const float*)d_in[0];
    const float* key_W = (const float*)d_in[1];
    const float* key_b = (const float*)d_in[2];
    const float* val_W = (const float*)d_in[3];
    const float* val_b = (const float*)d_in[4];
    const float* ln1_g = (const float*)d_in[5];
    const float* ln1_b = (const float*)d_in[6];
    const float* W1    = (const float*)d_in[7];
    const float* b1    = (const float*)d_in[8];
    const float* W2    = (const float*)d_in[9];
    const float* b2    = (const float*)d_in[10];
    const float* ln2_g = (const float*)d_in[11];
    const float* ln2_b = (const float*)d_in[12];
    const float* Wo    = (const float*)d_in[13];
    const float* bo    = (const float*)d_in[14];
    float* outp = (float*)d_out;

    float* ws = (float*)d_ws;
    float*  ph      = ws;                             // 262144 f32 (1 MB)
    float*  Mt      = ws + 262144;                    // 2097152 f32 (8 MB)
    ushort_t* Mpre_b = (ushort_t*)(Mt + 2097152);     // 2097152 us (4 MB)
    ushort_t* VoddT  = Mpre_b + 2097152;              // 524288 us (1 MB)
    ushort_t* rhat_b = VoddT + 524288;                // (layout hold)
    ushort_t* W1t   = rhat_b + 1048576;               // 131072 us
    ushort_t* W2t   = W1t + 131072;
    ushort_t* Wot   = W2t + 131072;
    ushort_t* valWt = Wot + 65536;

    prep_key_kernel<<<352, 256, 0, stream>>>(W1, W2, Wo, val_W, x, key_W, key_b,
                                             W1t, W2t, Wot, valWt, (float2*)ph);
    valbind_kernel<<<512, 256, 0, stream>>>(x, (const float2*)ph, valWt, val_b,
                                            VoddT, Mt);
    prefix_kernel<<<512, 256, 0, stream>>>(Mt, Mpre_b);
    retrieve_mlp_kernel<<<256, 512, 0, stream>>>(ph, Mpre_b, VoddT, ln1_g, ln1_b,
                                                 W1t, b1, W2t, b2, ln2_g, ln2_b,
                                                 Wot, bo, x, outp);
}